// Round 6
// baseline (63.007 us; speedup 1.0000x reference)
//
#include <hip/hip_runtime.h>

typedef float f32x4 __attribute__((ext_vector_type(4)));

// Problem dims (fixed by reference): bs=4, L=512, H=768, C=48
#define H_DIM 768
#define C_DIM 48
#define NROWS 2048          // bs * L
#define TWO_H 1536
#define WT_ELEMS (H_DIM * 96)   // 73728 floats

// ---------------------------------------------------------------------------
// Kernel 0: transpose W[48][1536] -> Wt[768][96] (k-major).
//   Wt[k][c] = W[c][k]        for c < 48   (i-half)
//   Wt[k][c] = W[c-48][768+k] for c >= 48  (j-half)
// Wt lives in the tail of d_out (bcast overwrites it afterwards).
// ---------------------------------------------------------------------------
__global__ __launch_bounds__(256) void wtrans_kernel(const float* __restrict__ W,
                                                     float* __restrict__ Wt) {
    const int idx = blockIdx.x * 256 + threadIdx.x;   // 0..18431
    const int c   = idx % 96;
    const int k   = (idx / 96) * 4;                   // 0..764
    const float* src = W + (size_t)(c % C_DIM) * TWO_H + (c / C_DIM) * H_DIM + k;
    const float4 v = *reinterpret_cast<const float4*>(src);
    Wt[(size_t)(k + 0) * 96 + c] = v.x;
    Wt[(size_t)(k + 1) * 96 + c] = v.y;
    Wt[(size_t)(k + 2) * 96 + c] = v.z;
    Wt[(size_t)(k + 3) * 96 + c] = v.w;
}

// ---------------------------------------------------------------------------
// Kernel 1: proj[half][row][c] = dot(hs[row,:], Wcol)   (unchanged from R5)
// grid = 512 blocks (4 rows each), block = 192 threads (3 waves).
// ---------------------------------------------------------------------------
#define PR_ROWS 4
#define PR_KG   4
#define PR_KSEG 192

__global__ __launch_bounds__(192) void proj_kernel(const float* __restrict__ hs,
                                                   const float* __restrict__ Wt,
                                                   float* __restrict__ proj) {
    __shared__ float hs_lds[PR_ROWS][H_DIM + 4];
    __shared__ float part[PR_KG][12][PR_ROWS][8];      // 6 KB

    const int t    = threadIdx.x;
    const int s    = t % 12;
    const int r    = (t / 12) & 3;
    const int kg   = t / 48;                           // 0..3
    const int row0 = blockIdx.x * PR_ROWS;

    {
        const f32x4* src = reinterpret_cast<const f32x4*>(hs + (size_t)row0 * H_DIM);
        #pragma unroll
        for (int rr = 0; rr < PR_ROWS; ++rr) {
            f32x4* dst = reinterpret_cast<f32x4*>(&hs_lds[rr][0]);
            dst[t] = src[rr * (H_DIM / 4) + t];
        }
    }
    __syncthreads();

    const f32x4* __restrict__ Wt4 = reinterpret_cast<const f32x4*>(Wt);

    float acc[8];
    #pragma unroll
    for (int e = 0; e < 8; ++e) acc[e] = 0.f;

    const int kbase = kg * PR_KSEG;
    for (int kk = 0; kk < PR_KSEG; kk += 4) {
        const int k = kbase + kk;
        const f32x4 h = *reinterpret_cast<const f32x4*>(&hs_lds[r][k]);
        #pragma unroll
        for (int j = 0; j < 4; ++j) {
            const f32x4 w0 = Wt4[(size_t)(k + j) * 24 + s];
            const f32x4 w1 = Wt4[(size_t)(k + j) * 24 + s + 12];
            const float hj = h[j];
            acc[0] += hj * w0.x;  acc[1] += hj * w0.y;
            acc[2] += hj * w0.z;  acc[3] += hj * w0.w;
            acc[4] += hj * w1.x;  acc[5] += hj * w1.y;
            acc[6] += hj * w1.z;  acc[7] += hj * w1.w;
        }
    }

    #pragma unroll
    for (int e = 0; e < 8; ++e) part[kg][s][r][e] = acc[e];
    __syncthreads();

    #pragma unroll
    for (int o = t; o < PR_ROWS * 96; o += 192) {
        const int rr   = o / 96;
        const int c    = o % 96;
        const int half = c / 48;
        const int cl   = c % 48;
        float v = 0.f;
        #pragma unroll
        for (int g = 0; g < PR_KG; ++g)
            v += part[g][cl >> 2][rr][half * 4 + (cl & 3)];
        proj[(size_t)half * (NROWS * C_DIM) + (size_t)(row0 + rr) * C_DIM + cl] = v;
    }
}

// ---------------------------------------------------------------------------
// Kernel 2 (v2): out[b,i,j,c] = proj_i[b,i,c] + proj_j[b,j,c] + bias[c]
// grid = 256 blocks: block = (b, group of 8 i-rows); block = 256 threads.
// The batch's proj_j slab (512*48 floats = 98 KB) is staged in LDS ONCE per
// block, so the 201 MB output write stream cannot evict it from L2 and force
// HBM re-fetches (the R5 failure mode). HBM traffic: ~201 MB writes + ~25 MB
// reads total.
// ---------------------------------------------------------------------------
#define IG 8                          // i-rows per block
#define SLAB_F4 (512 * C_DIM / 4)     // 6144 f32x4 = 98 KB

__global__ __launch_bounds__(256) void bcast_kernel(const float* __restrict__ proj,
                                                    const float* __restrict__ bias,
                                                    float* __restrict__ out) {
    __shared__ f32x4 slab[SLAB_F4];           // 98 KB: proj_j[b,:,:]
    __shared__ f32x4 rowi[IG][C_DIM / 4];     // (proj_i[b,i,:] + bias) x 8 rows

    const int t   = threadIdx.x;
    const int blk = blockIdx.x;               // 0..255
    const int b   = blk >> 6;                 // batch
    const int i0  = (blk & 63) * IG;          // first i-row of this block
    const int gi0 = b * 512 + i0;

    // Stage proj_j slab (coalesced f32x4, 24 insts/thread).
    {
        const f32x4* __restrict__ pj =
            reinterpret_cast<const f32x4*>(proj + (size_t)NROWS * C_DIM
                                                + (size_t)b * 512 * C_DIM);
        #pragma unroll
        for (int it = 0; it < SLAB_F4 / 256; ++it)
            slab[it * 256 + t] = pj[it * 256 + t];
    }
    // Stage 8 rows of (proj_i + bias): 96 f32x4.
    if (t < IG * (C_DIM / 4)) {
        const int r  = t / (C_DIM / 4);
        const int c4 = t % (C_DIM / 4);
        f32x4 pi = reinterpret_cast<const f32x4*>(proj + (size_t)(gi0 + r) * C_DIM)[c4];
        f32x4 bb = reinterpret_cast<const f32x4*>(bias)[c4];
        rowi[r][c4] = pi + bb;
    }
    __syncthreads();

    // 8 i-rows x 98 KB contiguous stores.
    for (int r = 0; r < IG; ++r) {
        f32x4* __restrict__ o =
            reinterpret_cast<f32x4*>(out) + (size_t)(gi0 + r) * SLAB_F4;
        #pragma unroll
        for (int it = 0; it < SLAB_F4 / 256; ++it) {
            const int p = it * 256 + t;
            o[p] = slab[p] + rowi[r][p % 12];
        }
    }
}

extern "C" void kernel_launch(void* const* d_in, const int* in_sizes, int n_in,
                              void* d_out, int out_size, void* d_ws, size_t ws_size,
                              hipStream_t stream) {
    const float* hs   = (const float*)d_in[0];   // (4, 512, 768) f32
    const float* W    = (const float*)d_in[1];   // (48, 1536)    f32
    const float* bias = (const float*)d_in[2];   // (48,)         f32
    float* out  = (float*)d_out;                 // (4,512,512,48) f32
    float* proj = (float*)d_ws;                  // 2*2048*48 floats = 786 KB

    // Wt lives in the tail of d_out; proj reads it before bcast overwrites it.
    float* Wt = out + (size_t)out_size - WT_ELEMS;

    wtrans_kernel<<<dim3(WT_ELEMS / 4 / 256), 256, 0, stream>>>(W, Wt);
    proj_kernel<<<dim3(NROWS / PR_ROWS), 192, 0, stream>>>(hs, Wt, proj);
    bcast_kernel<<<dim3(256), 256, 0, stream>>>(proj, bias, out);
}

// Round 7
// 54.207 us; speedup vs baseline: 1.1623x; 1.1623x over previous
//
#include <hip/hip_runtime.h>

typedef float f32x4 __attribute__((ext_vector_type(4)));

// Problem dims (fixed by reference): bs=4, L=512, H=768, C=48
#define H_DIM 768
#define C_DIM 48
#define NROWS 2048          // bs * L
#define TWO_H 1536
#define WT_ELEMS (H_DIM * 96)            // 73728 floats
#define PART_ELEMS (8 * NROWS * 96)      // 1572864 floats (8 k-slices)

// ---------------------------------------------------------------------------
// Kernel 0: transpose W[48][1536] -> Wt[768][96] (k-major).
//   Wt[k][c] = W[c][k] (c<48, i-half) ; Wt[k][c] = W[c-48][768+k] (c>=48)
// Wt lives in the tail of d_out (bcast overwrites it afterwards).
// ---------------------------------------------------------------------------
__global__ __launch_bounds__(256) void wtrans_kernel(const float* __restrict__ W,
                                                     float* __restrict__ Wt) {
    const int idx = blockIdx.x * 256 + threadIdx.x;   // 0..18431
    const int c   = idx % 96;
    const int k   = (idx / 96) * 4;                   // 0..764
    const float* src = W + (size_t)(c % C_DIM) * TWO_H + (c / C_DIM) * H_DIM + k;
    const float4 v = *reinterpret_cast<const float4*>(src);
    Wt[(size_t)(k + 0) * 96 + c] = v.x;
    Wt[(size_t)(k + 1) * 96 + c] = v.y;
    Wt[(size_t)(k + 2) * 96 + c] = v.z;
    Wt[(size_t)(k + 3) * 96 + c] = v.w;
}

// ---------------------------------------------------------------------------
// Kernel 1: split-k tiled GEMM.
// part[kg][row][c] = sum_{k in kg-slice} hs[row][k] * Wt[k][c]
// grid = 32 row-groups x 8 k-slices = 256 blocks (1/CU), block = 256 threads.
// BM=64 rows, 96 cols, k-slice = 96, BK=32, double-buffered LDS.
// Thread (r4 = t/16, c6 = t%16) owns a 4x6 register tile.
// Inner loop is pure LDS + FMA (no global loads) -> no L3-latency exposure.
// ---------------------------------------------------------------------------
#define BM 64
#define BK 32
#define KSLICE 96
#define NSTEP (KSLICE / BK)   // 3
#define LDA 33                // 32 + 1 pad
#define LDB 33

__global__ __launch_bounds__(256) void pgemm_kernel(const float* __restrict__ hs,
                                                    const float* __restrict__ Wt,
                                                    float* __restrict__ part) {
    __shared__ float A_lds[2][BM][LDA];   // 2 x 8.4 KB
    __shared__ float B_lds[2][96][LDB];   // 2 x 12.7 KB

    const int t    = threadIdx.x;
    const int kg   = blockIdx.x & 7;      // k-slice 0..7
    const int rg   = blockIdx.x >> 3;     // row-group 0..31
    const int row0 = rg * BM;
    const int kbase = kg * KSLICE;

    const int r4 = t >> 4;                // 0..15 (4 rows each)
    const int c6 = t & 15;                // 0..15 (6 cols each)

    const f32x4* __restrict__ hs4 = reinterpret_cast<const f32x4*>(hs);
    const f32x4* __restrict__ Wt4 = reinterpret_cast<const f32x4*>(Wt);

    // Staging thread roles
    const int a_row  = t >> 3;            // 0..31 (plus +32 on 2nd iter)
    const int a_kf4  = t & 7;             // f32x4 index within BK

    f32x4 a_reg[2], b_reg[3];

    // ---- load step 0 into regs ----
    {
        const int k0 = kbase;
        #pragma unroll
        for (int i = 0; i < 2; ++i)
            a_reg[i] = hs4[(size_t)(row0 + a_row + i * 32) * (H_DIM / 4) + (k0 >> 2) + a_kf4];
        #pragma unroll
        for (int i = 0; i < 3; ++i) {
            const int idx = i * 256 + t;          // 0..767
            const int kk  = idx / 24;
            const int c4  = idx % 24;
            b_reg[i] = Wt4[(size_t)(k0 + kk) * 24 + c4];
        }
    }
    // ---- write step 0 to LDS buf 0 ----
    {
        #pragma unroll
        for (int i = 0; i < 2; ++i)
            *reinterpret_cast<f32x4*>(&A_lds[0][a_row + i * 32][a_kf4 * 4]) = a_reg[i];
        #pragma unroll
        for (int i = 0; i < 3; ++i) {
            const int idx = i * 256 + t;
            const int kk  = idx / 24;
            const int c4  = idx % 24;
            #pragma unroll
            for (int m = 0; m < 4; ++m)
                B_lds[0][c4 * 4 + m][kk] = b_reg[i][m];
        }
    }

    float acc[4][6];
    #pragma unroll
    for (int ri = 0; ri < 4; ++ri)
        #pragma unroll
        for (int j = 0; j < 6; ++j) acc[ri][j] = 0.f;

    for (int s = 0; s < NSTEP; ++s) {
        __syncthreads();

        // Prefetch step s+1 into regs (overlaps with compute below).
        if (s + 1 < NSTEP) {
            const int k0 = kbase + (s + 1) * BK;
            #pragma unroll
            for (int i = 0; i < 2; ++i)
                a_reg[i] = hs4[(size_t)(row0 + a_row + i * 32) * (H_DIM / 4) + (k0 >> 2) + a_kf4];
            #pragma unroll
            for (int i = 0; i < 3; ++i) {
                const int idx = i * 256 + t;
                const int kk  = idx / 24;
                const int c4  = idx % 24;
                b_reg[i] = Wt4[(size_t)(k0 + kk) * 24 + c4];
            }
        }

        // Compute step s from LDS.
        const int buf = s & 1;
        #pragma unroll
        for (int kk4 = 0; kk4 < BK / 4; ++kk4) {
            f32x4 a[4], b[6];
            #pragma unroll
            for (int ri = 0; ri < 4; ++ri)
                a[ri] = *reinterpret_cast<const f32x4*>(&A_lds[buf][r4 * 4 + ri][kk4 * 4]);
            #pragma unroll
            for (int j = 0; j < 6; ++j)
                b[j] = *reinterpret_cast<const f32x4*>(&B_lds[buf][c6 * 6 + j][kk4 * 4]);
            #pragma unroll
            for (int ri = 0; ri < 4; ++ri)
                #pragma unroll
                for (int j = 0; j < 6; ++j) {
                    acc[ri][j] += a[ri].x * b[j].x;
                    acc[ri][j] += a[ri].y * b[j].y;
                    acc[ri][j] += a[ri].z * b[j].z;
                    acc[ri][j] += a[ri].w * b[j].w;
                }
        }

        __syncthreads();

        // Write prefetched regs into the other LDS buffer.
        if (s + 1 < NSTEP) {
            const int buf2 = (s + 1) & 1;
            #pragma unroll
            for (int i = 0; i < 2; ++i)
                *reinterpret_cast<f32x4*>(&A_lds[buf2][a_row + i * 32][a_kf4 * 4]) = a_reg[i];
            #pragma unroll
            for (int i = 0; i < 3; ++i) {
                const int idx = i * 256 + t;
                const int kk  = idx / 24;
                const int c4  = idx % 24;
                #pragma unroll
                for (int m = 0; m < 4; ++m)
                    B_lds[buf2][c4 * 4 + m][kk] = b_reg[i][m];
            }
        }
    }

    // Epilogue: write the 4x6 tile to this k-slice's partial slab.
    float* __restrict__ pslab = part + (size_t)kg * (NROWS * 96);
    #pragma unroll
    for (int ri = 0; ri < 4; ++ri) {
        const int row = row0 + r4 * 4 + ri;
        #pragma unroll
        for (int j = 0; j < 6; ++j)
            pslab[(size_t)row * 96 + c6 * 6 + j] = acc[ri][j];
    }
}

// ---------------------------------------------------------------------------
// Kernel 1b: reduce 8 k-slice partials -> proj[half][row][cl]
// 49152 f32x4 outputs; grid = 192 x 256, one f32x4 per thread.
// ---------------------------------------------------------------------------
__global__ __launch_bounds__(256) void preduce_kernel(const float* __restrict__ part,
                                                      float* __restrict__ proj) {
    const int p = blockIdx.x * 256 + threadIdx.x;     // 0..49151
    const f32x4* __restrict__ part4 = reinterpret_cast<const f32x4*>(part);

    f32x4 v = part4[p];
    #pragma unroll
    for (int g = 1; g < 8; ++g)
        v += part4[(size_t)g * (NROWS * 96 / 4) + p];

    const int row  = p / 24;
    const int c4   = p % 24;
    const int half = c4 / 12;
    const int cl4  = c4 % 12;
    reinterpret_cast<f32x4*>(proj)[(size_t)half * (NROWS * 12) + (size_t)row * 12 + cl4] = v;
}

// ---------------------------------------------------------------------------
// Kernel 2: out[b,i,j,c] = proj_i[b,i,c] + proj_j[b,j,c] + bias[c]
// R4 version (best measured): one block per (b,i), 2048 x 256.
// ---------------------------------------------------------------------------
__global__ __launch_bounds__(256) void bcast_kernel(const float* __restrict__ proj,
                                                    const float* __restrict__ bias,
                                                    float* __restrict__ out) {
    const int gi = blockIdx.x;          // b*512 + i
    const int b  = gi >> 9;

    __shared__ f32x4 rowi[C_DIM / 4];   // proj_i[b,i,:] + bias  (12 f32x4)

    const int t = threadIdx.x;
    if (t < C_DIM / 4) {
        f32x4 pi = reinterpret_cast<const f32x4*>(proj + (size_t)gi * C_DIM)[t];
        f32x4 bb = reinterpret_cast<const f32x4*>(bias)[t];
        rowi[t] = pi + bb;
    }
    __syncthreads();

    const f32x4* __restrict__ pj =
        reinterpret_cast<const f32x4*>(proj + (size_t)NROWS * C_DIM
                                            + (size_t)b * 512 * C_DIM);
    f32x4* __restrict__ o =
        reinterpret_cast<f32x4*>(out) + (size_t)gi * (512 * C_DIM / 4);

    constexpr int SLAB_F4 = 512 * C_DIM / 4;   // 6144
    #pragma unroll
    for (int it = 0; it < SLAB_F4 / 256; ++it) {
        const int p  = it * 256 + t;
        const int c4 = p % 12;
        o[p] = pj[p] + rowi[c4];
    }
}

extern "C" void kernel_launch(void* const* d_in, const int* in_sizes, int n_in,
                              void* d_out, int out_size, void* d_ws, size_t ws_size,
                              hipStream_t stream) {
    const float* hs   = (const float*)d_in[0];   // (4, 512, 768) f32
    const float* W    = (const float*)d_in[1];   // (48, 1536)    f32
    const float* bias = (const float*)d_in[2];   // (48,)         f32
    float* out  = (float*)d_out;                 // (4,512,512,48) f32
    float* proj = (float*)d_ws;                  // 2*2048*48 floats = 786 KB

    // Scratch in the d_out tail (read before bcast overwrites it):
    //   [... out ... | part (6.29 MB) | Wt (295 KB)]
    float* Wt   = out + (size_t)out_size - WT_ELEMS;
    float* part = Wt - PART_ELEMS;

    wtrans_kernel<<<dim3(WT_ELEMS / 4 / 256), 256, 0, stream>>>(W, Wt);
    pgemm_kernel<<<dim3(256), 256, 0, stream>>>(hs, Wt, part);
    preduce_kernel<<<dim3(192), 256, 0, stream>>>(part, proj);
    bcast_kernel<<<dim3(NROWS), 256, 0, stream>>>(proj, bias, out);
}